// Round 2
// baseline (24.626 us; speedup 1.0000x reference)
//
#include <hip/hip_runtime.h>

// out[i, j] = (j >= k_i) ? 1 : 0 with k_i = (int)(rint(x_i*8)/8 * 2048)
//           = rint(x_i*8) * 256  -> always a multiple of 256.
// jnp.round = round-half-to-even = rintf (default RNE rounding mode).
// Output 8192 x 4096 fp32 = 128 MiB -> pure HBM-write-bound.
// k is a multiple of 256 -> every float4 in a row is uniform (no lane masks).

#define IN_CHANNEL 4096
#define BATCH 8192
#define ROW_F4 (IN_CHANNEL / 4)   // 1024 float4 per row

// One block per row: 256 threads x 4 float4 each = 1024 float4 = one row.
// x[row] is a single wave-uniform load per block (L1/L2 broadcast).
__global__ void __launch_bounds__(256) embprob_kernel(
    const float* __restrict__ x, float4* __restrict__ out) {
    const int row = blockIdx.x;
    const float xv = x[row];
    const int k = (int)rintf(xv * 8.0f) * 256;   // cutoff column, multiple of 256

    float4* rowp = out + (size_t)row * ROW_F4;
    const int t = threadIdx.x;
    #pragma unroll
    for (int u = 0; u < 4; ++u) {
        const int f4 = t + u * 256;              // float4 index within row
        const int col = f4 << 2;                 // element column
        const float v = (col >= k) ? 1.0f : 0.0f;
        rowp[f4] = make_float4(v, v, v, v);
    }
}

extern "C" void kernel_launch(void* const* d_in, const int* in_sizes, int n_in,
                              void* d_out, int out_size, void* d_ws, size_t ws_size,
                              hipStream_t stream) {
    const float* x = (const float*)d_in[0];
    float4* out = (float4*)d_out;
    embprob_kernel<<<BATCH, 256, 0, stream>>>(x, out);
}